// Round 12
// baseline (336.374 us; speedup 1.0000x reference)
//
#include <hip/hip_runtime.h>

// ---------------------------------------------------------------------------
// out = 0.5*F + 0.5*softmax((F Wq^T)(M Wk^T)^T) M ;  N=M=8192, H=512, fp32.
// R15: R14 minus the XCD remap (measured -11 µs on flash; identity mapping
// restored). Flash = R11's proven 2-barrier schedule byte-identical.
// Kept: castpack fusion (R13, +12 µs win), proj z-fusion (R11).
// Flash schedule per tile:
//   BAR1 = s_waitcnt vmcnt(8) lgkmcnt(0); s_barrier
//     rescale(o) gated by flagw; PV(t-1) [vlds+plds] || QK(t) [klds];
//     softmax(t); P->plds[t&1]
//   BAR2 = s_waitcnt lgkmcnt(0); s_barrier
//     issue DMA V(t+1), K(t+2)     (counted vmcnt keeps them in flight)
// ---------------------------------------------------------------------------

typedef _Float16 half8 __attribute__((ext_vector_type(8)));
typedef _Float16 half4 __attribute__((ext_vector_type(4)));
typedef float floatx4 __attribute__((ext_vector_type(4)));

#define MFMA16(a, b, c) __builtin_amdgcn_mfma_f32_16x16x32_f16((a), (b), (c), 0, 0, 0)

static constexpr int H = 512;
static constexpr int NROWS = 8192;

__device__ __forceinline__ void dma16(half8* lds_dst, const void* g_src) {
    __builtin_amdgcn_global_load_lds(
        (const __attribute__((address_space(1))) unsigned int*)g_src,
        (__attribute__((address_space(3))) unsigned int*)lds_dst,
        16, 0, 0);
}

// ---------------------------------------------------------------------------
// K0: fused cast + V-pack.
// Blocks [0, 8704): cast F, Mem, Wq, Wk (fp32) to fp16, 4 elems/thread.
// Blocks [8704, 10752): pack V fp32->fp16 into MFMA B-frag order:
//   vp[kb*2048 + db*64 + g*16 + c][j] = Mem[(kb*32+g*8+j)*512 + db*16 + c]
// ---------------------------------------------------------------------------
__global__ void castpack_kernel(const float* __restrict__ F, const float* __restrict__ Mem,
                                const float* __restrict__ wq, const float* __restrict__ wk,
                                _Float16* __restrict__ f16, _Float16* __restrict__ m16,
                                _Float16* __restrict__ wq16, _Float16* __restrict__ wk16,
                                half8* __restrict__ vp) {
    if (blockIdx.x < 8704) {
        size_t i4 = (size_t)(blockIdx.x * 256 + threadIdx.x) * 4;
        const float* src; _Float16* dst; size_t off;
        if (i4 < 4194304ull)       { src = F;   dst = f16;  off = i4; }
        else if (i4 < 8388608ull)  { src = Mem; dst = m16;  off = i4 - 4194304ull; }
        else if (i4 < 8650752ull)  { src = wq;  dst = wq16; off = i4 - 8388608ull; }
        else                       { src = wk;  dst = wk16; off = i4 - 8650752ull; }
        float4 v = *(const float4*)&src[off];
        half4 h;
        h[0] = (_Float16)v.x; h[1] = (_Float16)v.y; h[2] = (_Float16)v.z; h[3] = (_Float16)v.w;
        *(half4*)&dst[off] = h;
    } else {
        int cid = (blockIdx.x - 8704) * 256 + threadIdx.x;
        int kb  = cid >> 11;
        int rem = cid & 2047;
        int db  = rem >> 6;
        int gc  = rem & 63;
        int g   = gc >> 4, c = gc & 15;
        const float* src = Mem + (size_t)(kb * 32 + g * 8) * H + db * 16 + c;
        half8 v;
#pragma unroll
        for (int j = 0; j < 8; ++j) v[j] = (_Float16)src[(size_t)j * H];
        vp[cid] = v;
    }
}

// ---------------------------------------------------------------------------
// K1: both projection GEMMs in one launch (blockIdx.z selects q/k problem).
// out = fp16(X16 @ W16^T + b). fp16 A-loads, 32 rows/wave. Grid (64, 8, 2).
// ---------------------------------------------------------------------------
__global__ __launch_bounds__(256, 4)
void proj_kernel(const _Float16* __restrict__ Xq, const _Float16* __restrict__ Wq16,
                 const float* __restrict__ bq, _Float16* __restrict__ oq,
                 const _Float16* __restrict__ Xk, const _Float16* __restrict__ Wk16,
                 const float* __restrict__ bk, _Float16* __restrict__ ok) {
    const _Float16* X16 = blockIdx.z ? Xk : Xq;
    const _Float16* W16 = blockIdx.z ? Wk16 : Wq16;
    const float*    bias = blockIdx.z ? bk : bq;
    _Float16*       out = blockIdx.z ? ok : oq;

    const int lane = threadIdx.x & 63;
    const int wave = threadIdx.x >> 6;
    const int row0 = blockIdx.x * 128 + wave * 32;
    const int col0 = blockIdx.y * 64;
    const int lr = lane & 15, lq = lane >> 4;

    floatx4 acc[2][4];
#pragma unroll
    for (int rt = 0; rt < 2; ++rt)
#pragma unroll
        for (int nt = 0; nt < 4; ++nt) { acc[rt][nt][0] = 0.f; acc[rt][nt][1] = 0.f; acc[rt][nt][2] = 0.f; acc[rt][nt][3] = 0.f; }

    const half8* ar0 = (const half8*)(X16 + (size_t)(row0 + lr) * H) + lq;
    const half8* ar1 = (const half8*)(X16 + (size_t)(row0 + 16 + lr) * H) + lq;
    const half8* wbase = (const half8*)W16;

#pragma unroll
    for (int kk = 0; kk < 16; ++kk) {
        half8 a0 = ar0[kk * 4];
        half8 a1 = ar1[kk * 4];
#pragma unroll
        for (int nt = 0; nt < 4; ++nt) {
            half8 bf = wbase[(size_t)(col0 + nt * 16 + lr) * 64 + kk * 4 + lq];
            acc[0][nt] = MFMA16(a0, bf, acc[0][nt]);
            acc[1][nt] = MFMA16(a1, bf, acc[1][nt]);
        }
    }
#pragma unroll
    for (int rt = 0; rt < 2; ++rt)
#pragma unroll
        for (int nt = 0; nt < 4; ++nt) {
            int col = col0 + nt * 16 + lr;
            float b = bias[col];
#pragma unroll
            for (int r = 0; r < 4; ++r) {
                int row = row0 + rt * 16 + lq * 4 + r;
                out[(size_t)row * H + col] = (_Float16)(acc[rt][nt][r] + b);
            }
        }
}

// ---------------------------------------------------------------------------
// K2: flash attention, 2-barrier pipelined (R11 schedule, verbatim).
// blockIdx.x = rbk*4+slice; 128 q-rows per block (8 waves x 16-row stripe),
// slice owns 2048 keys as 64 tiles of 32 keys.
// ---------------------------------------------------------------------------
__global__ __launch_bounds__(512, 2)
void flash_kernel(const _Float16* __restrict__ q16, const _Float16* __restrict__ k16,
                  const half8* __restrict__ vp, _Float16* __restrict__ opart,
                  float* __restrict__ mpart, float* __restrict__ lpart) {
    __shared__ half8 klds[2][2048];        // 2 x 32 KB: K tiles, B-frag order
    __shared__ half8 vlds[2][2048];        // 2 x 32 KB: V tiles, packed order
    __shared__ _Float16 plds[2][128 * 36]; // 2 x 9 KB: P, stride 36
    __shared__ float alds[2][128];         // per-row rescale factors, dbuf
    __shared__ float llds[128];            // final per-row l
    __shared__ int flagw[2][8];            // per-wave trigger flag, dbuf

    const int tid = threadIdx.x;
    const int lane = tid & 63;
    const int wave = tid >> 6;
    const int rbk = blockIdx.x >> 2;
    const int slice = blockIdx.x & 3;
    const int row0 = rbk * 128;
    const int lr = lane & 15, lq = lane >> 4;

    // K-DMA source offsets: LDS dst d = tid+i*512 -> (c,kk,g,cc);
    // src = (c*16+cc)*512 + kk*32 + g*8 halves within the 32-key K tile.
    int koff[4];
#pragma unroll
    for (int i = 0; i < 4; ++i) {
        int d = tid + i * 512;
        int c = d >> 10, kk = (d >> 6) & 15, g = (d >> 4) & 3, cc = d & 15;
        koff[i] = c * 8192 + cc * 512 + kk * 32 + g * 8;
    }

    // Q stripe for QK: lane holds q16[row0+wave*16+lr][kk*32+lq*8 ..]
    const half8* qrow = (const half8*)(q16 + (size_t)(row0 + wave * 16 + lr) * H);
    half8 qf[16];
#pragma unroll
    for (int kk = 0; kk < 16; ++kk) qf[kk] = qrow[kk * 4 + lq];

    floatx4 o[8][4];
#pragma unroll
    for (int rb = 0; rb < 8; ++rb)
#pragma unroll
        for (int f = 0; f < 4; ++f) { o[rb][f][0] = 0.f; o[rb][f][1] = 0.f; o[rb][f][2] = 0.f; o[rb][f][3] = 0.f; }
    float m[4], l[4];
#pragma unroll
    for (int r = 0; r < 4; ++r) { m[r] = -1e30f; l[r] = 0.f; }

    // prologue DMA: K(0) -> klds[0], V(0) -> vlds[0], K(1) -> klds[1]
    {
        const int kt0 = slice * 64;
        const _Float16* ksrc0 = k16 + (size_t)kt0 * 16384;
        const half8* vsrc0 = vp + (size_t)kt0 * 2048;
#pragma unroll
        for (int i = 0; i < 4; ++i) dma16(&klds[0][tid + i * 512], ksrc0 + koff[i]);
#pragma unroll
        for (int i = 0; i < 4; ++i) dma16(&vlds[0][tid + i * 512], &vsrc0[tid + i * 512]);
        const _Float16* ksrc1 = k16 + (size_t)(kt0 + 1) * 16384;
#pragma unroll
        for (int i = 0; i < 4; ++i) dma16(&klds[1][tid + i * 512], ksrc1 + koff[i]);
    }

    for (int tt = 0; tt < 64; ++tt) {
        const int b = tt & 1;

        // BAR1: keep 8 newest loads (V(tt), K(tt+1)) in flight; older drained.
        asm volatile("s_waitcnt vmcnt(8) lgkmcnt(0)" ::: "memory");
        __builtin_amdgcn_s_barrier();

        if (tt > 0) {
            const int q1 = b ^ 1;
            // ---- deferred rescale, gated per 16-row chunk (overlapped) ----
#pragma unroll
            for (int rb = 0; rb < 8; ++rb) {
                if (flagw[q1][rb]) {
                    float a0 = alds[q1][rb * 16 + lq * 4 + 0];
                    float a1 = alds[q1][rb * 16 + lq * 4 + 1];
                    float a2 = alds[q1][rb * 16 + lq * 4 + 2];
                    float a3 = alds[q1][rb * 16 + lq * 4 + 3];
#pragma unroll
                    for (int f = 0; f < 4; ++f) {
                        o[rb][f][0] *= a0; o[rb][f][1] *= a1;
                        o[rb][f][2] *= a2; o[rb][f][3] *= a3;
                    }
                }
            }
            // ---- PV(tt-1): overlaps QK ds_reads ----
            __builtin_amdgcn_s_setprio(1);
            half8 vf[4];
#pragma unroll
            for (int f = 0; f < 4; ++f) vf[f] = vlds[q1][(wave * 4 + f) * 64 + lane];
#pragma unroll
            for (int rb = 0; rb < 8; ++rb) {
                half8 pfr = *(const half8*)&plds[q1][(rb * 16 + lr) * 36 + lq * 8];
#pragma unroll
                for (int f = 0; f < 4; ++f) o[rb][f] = MFMA16(pfr, vf[f], o[rb][f]);
            }
            __builtin_amdgcn_s_setprio(0);
        }

        // ---- QK^T(tt): S[16 x 32] per wave, K frags from klds[b] ----
        __builtin_amdgcn_s_setprio(1);
        floatx4 s0 = {0.f, 0.f, 0.f, 0.f}, s1 = {0.f, 0.f, 0.f, 0.f};
#pragma unroll
        for (int kk = 0; kk < 16; ++kk) {
            s0 = MFMA16(qf[kk], klds[b][kk * 64 + lane], s0);
            s1 = MFMA16(qf[kk], klds[b][1024 + kk * 64 + lane], s1);
        }
        __builtin_amdgcn_s_setprio(0);

        // ---- softmax(tt): per-wave trigger (16 rows) ----
        float tm[4]; int trig = 0;
#pragma unroll
        for (int r = 0; r < 4; ++r) {
            tm[r] = fmaxf(s0[r], s1[r]);
            trig |= (tm[r] > m[r] + 10.f) ? 1 : 0;
        }
        const int trigany = __any(trig) ? 1 : 0;
        if (lane == 0) flagw[b][wave] = trigany;
        if (trigany) {
            float al[4];
#pragma unroll
            for (int r = 0; r < 4; ++r) {
                float mx = tm[r];
                mx = fmaxf(mx, __shfl_xor(mx, 1));
                mx = fmaxf(mx, __shfl_xor(mx, 2));
                mx = fmaxf(mx, __shfl_xor(mx, 4));
                mx = fmaxf(mx, __shfl_xor(mx, 8));
                float mn = (mx > m[r] + 10.f) ? mx : m[r];
                al[r] = __expf(m[r] - mn);
                m[r] = mn;
                l[r] *= al[r];
            }
            if (lr == 0) {
#pragma unroll
                for (int r = 0; r < 4; ++r) alds[b][wave * 16 + lq * 4 + r] = al[r];
            }
        }

        // ---- exp, l accumulate, P -> plds[b] (overlapped; dbuf) ----
#pragma unroll
        for (int r = 0; r < 4; ++r) {
            float p0 = __expf(s0[r] - m[r]);
            float p1 = __expf(s1[r] - m[r]);
            l[r] += p0 + p1;
            plds[b][(wave * 16 + lq * 4 + r) * 36 + lr]      = (_Float16)p0;
            plds[b][(wave * 16 + lq * 4 + r) * 36 + 16 + lr] = (_Float16)p1;
        }

        // BAR2: all waves' klds[b]/vlds[b^1] reads consumed; LDS writes landed.
        asm volatile("s_waitcnt lgkmcnt(0)" ::: "memory");
        __builtin_amdgcn_s_barrier();

        // ---- issue DMA: V(tt+1) -> vlds[(tt+1)&1], K(tt+2) -> klds[b] ----
        // Tail-clamped (dead-buffer writes) to keep vmcnt count uniform at 8.
        {
            int vt = tt + 1; if (vt > 63) vt = 63;
            int kt2 = tt + 2; if (kt2 > 63) kt2 = 63;
            const half8* vsrc = vp + (size_t)(slice * 64 + vt) * 2048;
#pragma unroll
            for (int i = 0; i < 4; ++i) dma16(&vlds[(tt + 1) & 1][tid + i * 512], &vsrc[tid + i * 512]);
            const _Float16* ksrc = k16 + (size_t)(slice * 64 + kt2) * 16384;
#pragma unroll
            for (int i = 0; i < 4; ++i) dma16(&klds[b][tid + i * 512], ksrc + koff[i]);
        }
    }

    // ---- epilogue: rescale(63) + PV(63); all P/alds/flagw written pre-BAR2(63)
    asm volatile("s_waitcnt lgkmcnt(0)" ::: "memory");
    {
#pragma unroll
        for (int rb = 0; rb < 8; ++rb) {
            if (flagw[1][rb]) {
                float a0 = alds[1][rb * 16 + lq * 4 + 0];
                float a1 = alds[1][rb * 16 + lq * 4 + 1];
                float a2 = alds[1][rb * 16 + lq * 4 + 2];
                float a3 = alds[1][rb * 16 + lq * 4 + 3];
#pragma unroll
                for (int f = 0; f < 4; ++f) {
                    o[rb][f][0] *= a0; o[rb][f][1] *= a1;
                    o[rb][f][2] *= a2; o[rb][f][3] *= a3;
                }
            }
        }
        __builtin_amdgcn_s_setprio(1);
        half8 vf[4];
#pragma unroll
        for (int f = 0; f < 4; ++f) vf[f] = vlds[1][(wave * 4 + f) * 64 + lane];
#pragma unroll
        for (int rb = 0; rb < 8; ++rb) {
            half8 pfr = *(const half8*)&plds[1][(rb * 16 + lr) * 36 + lq * 8];
#pragma unroll
            for (int f = 0; f < 4; ++f) o[rb][f] = MFMA16(pfr, vf[f], o[rb][f]);
        }
        __builtin_amdgcn_s_setprio(0);
    }

    // ---- final l reduction over the 16 lr lanes ----
#pragma unroll
    for (int r = 0; r < 4; ++r) {
        float lv = l[r];
        lv += __shfl_xor(lv, 1); lv += __shfl_xor(lv, 2);
        lv += __shfl_xor(lv, 4); lv += __shfl_xor(lv, 8);
        l[r] = lv;
    }
    if (lr == 0) {
#pragma unroll
        for (int r = 0; r < 4; ++r) {
            int row = wave * 16 + lq * 4 + r;
            llds[row] = l[r];
            mpart[slice * NROWS + row0 + row] = m[r];
            lpart[slice * NROWS + row0 + row] = l[r];
        }
    }
    __syncthreads();

    // ---- normalized O store (fp16); wave owns d-slice [wave*64, +64) ----
    _Float16* ob = opart + (size_t)slice * NROWS * H;
#pragma unroll
    for (int rb = 0; rb < 8; ++rb) {
#pragma unroll
        for (int rr = 0; rr < 4; ++rr) {
            float linv = 1.0f / llds[rb * 16 + lq * 4 + rr];
            size_t row = row0 + rb * 16 + lq * 4 + rr;
#pragma unroll
            for (int f = 0; f < 4; ++f)
                ob[row * H + wave * 64 + f * 16 + lr] = (_Float16)(o[rb][f][rr] * linv);
        }
    }
}

// ---------------------------------------------------------------------------
// K3: merge normalized slice partials, 4 outputs/thread, vectorized.
// ---------------------------------------------------------------------------
__global__ void merge_kernel(const _Float16* __restrict__ opart, const float* __restrict__ mpart,
                             const float* __restrict__ lpart, const float* __restrict__ F,
                             float* __restrict__ out) {
    int gid = blockIdx.x * 256 + threadIdx.x;
    size_t idx4 = (size_t)gid * 4;
    int row = (int)(idx4 >> 9);
    float m0 = mpart[row], m1 = mpart[NROWS + row], m2 = mpart[2 * NROWS + row], m3 = mpart[3 * NROWS + row];
    float ms = fmaxf(fmaxf(m0, m1), fmaxf(m2, m3));
    float w0 = __expf(m0 - ms) * lpart[row];
    float w1 = __expf(m1 - ms) * lpart[NROWS + row];
    float w2 = __expf(m2 - ms) * lpart[2 * NROWS + row];
    float w3 = __expf(m3 - ms) * lpart[3 * NROWS + row];
    float rdenom = 1.0f / (w0 + w1 + w2 + w3);
    size_t stride = (size_t)NROWS * H;
    half4 o0 = *(const half4*)&opart[idx4];
    half4 o1 = *(const half4*)&opart[stride + idx4];
    half4 o2 = *(const half4*)&opart[2 * stride + idx4];
    half4 o3 = *(const half4*)&opart[3 * stride + idx4];
    float4 Fv = *(const float4*)&F[idx4];
    float4 res;
    res.x = 0.5f * Fv.x + 0.5f * ((w0 * (float)o0[0] + w1 * (float)o1[0] + w2 * (float)o2[0] + w3 * (float)o3[0]) * rdenom);
    res.y = 0.5f * Fv.y + 0.5f * ((w0 * (float)o0[1] + w1 * (float)o1[1] + w2 * (float)o2[1] + w3 * (float)o3[1]) * rdenom);
    res.z = 0.5f * Fv.z + 0.5f * ((w0 * (float)o0[2] + w1 * (float)o1[2] + w2 * (float)o2[2] + w3 * (float)o3[2]) * rdenom);
    res.w = 0.5f * Fv.w + 0.5f * ((w0 * (float)o0[3] + w1 * (float)o1[3] + w2 * (float)o2[3] + w3 * (float)o3[3]) * rdenom);
    *(float4*)&out[idx4] = res;
}

// ---------------------------------------------------------------------------
// Workspace (~58 MB):
//   [ 0M,  8M) q16   [ 8M, 16M) k16   [16M, 24M) vp   [24M, 56M) opart fp16
//   f16F aliases opart[24M,32M), m16 aliases opart[32M,40M) — both dead
//   before flash_kernel writes opart (stream-ordered).
//   [56M,+128K) mpart  [+128K] lpart  [57M,+1M) wq16/wk16
// ---------------------------------------------------------------------------
extern "C" void kernel_launch(void* const* d_in, const int* in_sizes, int n_in,
                              void* d_out, int out_size, void* d_ws, size_t ws_size,
                              hipStream_t stream) {
    const float* F   = (const float*)d_in[0];
    const float* Mem = (const float*)d_in[1];
    const float* Wq  = (const float*)d_in[2];
    const float* bq  = (const float*)d_in[3];
    const float* Wk  = (const float*)d_in[4];
    const float* bk  = (const float*)d_in[5];
    float* out = (float*)d_out;

    char* ws = (char*)d_ws;
    _Float16* q16   = (_Float16*)(ws);
    _Float16* k16   = (_Float16*)(ws + (8ull << 20));
    half8*    vp    = (half8*)(ws + (16ull << 20));
    _Float16* opart = (_Float16*)(ws + (24ull << 20));
    _Float16* f16F  = (_Float16*)(ws + (24ull << 20));   // aliases opart slice 0
    _Float16* m16   = (_Float16*)(ws + (32ull << 20));   // aliases opart slice 1
    float*    mpart = (float*)(ws + (56ull << 20));
    float*    lpart = (float*)(ws + (56ull << 20) + (128ull << 10));
    _Float16* wq16  = (_Float16*)(ws + (57ull << 20));
    _Float16* wk16  = (_Float16*)(ws + (57ull << 20) + (512ull << 10));

    castpack_kernel<<<10752, 256, 0, stream>>>(F, Mem, Wq, Wk, f16F, m16, wq16, wk16, vp);
    proj_kernel<<<dim3(64, 8, 2), 256, 0, stream>>>(f16F, wq16, bq, q16, m16, wk16, bk, k16);
    flash_kernel<<<256, 512, 0, stream>>>(q16, k16, vp, opart, mpart, lpart);
    merge_kernel<<<4096, 256, 0, stream>>>(opart, mpart, lpart, F, out);
}

// Round 13
// 314.289 us; speedup vs baseline: 1.0703x; 1.0703x over previous
//
#include <hip/hip_runtime.h>

// ---------------------------------------------------------------------------
// out = 0.5*F + 0.5*softmax((F Wq^T)(M Wk^T)^T) M ;  N=M=8192, H=512, fp32.
// R16: R15 + coalesced proj B-loads. W is repacked at cast time into
// wpk[col>>4][j=kk*4+lq][col&15] (half8 units) so a B-frag wave-load reads
// one contiguous 1 KB block (was a 16-line gather at 1 KB stride).
// Flash = R11 2-barrier schedule, byte-identical (212.6 µs, triple-confirmed).
// ---------------------------------------------------------------------------

typedef _Float16 half8 __attribute__((ext_vector_type(8)));
typedef _Float16 half4 __attribute__((ext_vector_type(4)));
typedef float floatx4 __attribute__((ext_vector_type(4)));

#define MFMA16(a, b, c) __builtin_amdgcn_mfma_f32_16x16x32_f16((a), (b), (c), 0, 0, 0)

static constexpr int H = 512;
static constexpr int NROWS = 8192;

__device__ __forceinline__ void dma16(half8* lds_dst, const void* g_src) {
    __builtin_amdgcn_global_load_lds(
        (const __attribute__((address_space(1))) unsigned int*)g_src,
        (__attribute__((address_space(3))) unsigned int*)lds_dst,
        16, 0, 0);
}

// ---------------------------------------------------------------------------
// K0: fused cast + V-pack.
// Blocks [0, 8704): cast F, Mem (fp32->fp16, layout-preserving) and Wq, Wk
//   (fp32->fp16 into PACKED layout: half8 unit index colb*1024 + j*16 + ci,
//   colb=col>>4, ci=col&15, j=in>>3 — so proj B-loads are coalesced).
// Blocks [8704, 10752): pack V fp32->fp16 into MFMA B-frag order:
//   vp[kb*2048 + db*64 + g*16 + c][j] = Mem[(kb*32+g*8+j)*512 + db*16 + c]
// ---------------------------------------------------------------------------
__global__ void castpack_kernel(const float* __restrict__ F, const float* __restrict__ Mem,
                                const float* __restrict__ wq, const float* __restrict__ wk,
                                _Float16* __restrict__ f16, _Float16* __restrict__ m16,
                                _Float16* __restrict__ wq16, _Float16* __restrict__ wk16,
                                half8* __restrict__ vp) {
    if (blockIdx.x < 8704) {
        size_t i4 = (size_t)(blockIdx.x * 256 + threadIdx.x) * 4;
        if (i4 < 8388608ull) {
            // F / Mem: straight cast, layout-preserving
            const float* src; _Float16* dst; size_t off;
            if (i4 < 4194304ull) { src = F;   dst = f16; off = i4; }
            else                 { src = Mem; dst = m16; off = i4 - 4194304ull; }
            float4 v = *(const float4*)&src[off];
            half4 h;
            h[0] = (_Float16)v.x; h[1] = (_Float16)v.y; h[2] = (_Float16)v.z; h[3] = (_Float16)v.w;
            *(half4*)&dst[off] = h;
        } else {
            // Wq / Wk: cast into packed B-frag layout
            const float* src; _Float16* dst; size_t off;
            if (i4 < 8650752ull) { src = wq; dst = wq16; off = i4 - 8388608ull; }
            else                 { src = wk; dst = wk16; off = i4 - 8650752ull; }
            int col = (int)(off >> 9);        // W row-major [col][in], 512 wide
            int in0 = (int)(off & 511);       // multiple of 4
            float4 v = *(const float4*)&src[off];
            half4 h;
            h[0] = (_Float16)v.x; h[1] = (_Float16)v.y; h[2] = (_Float16)v.z; h[3] = (_Float16)v.w;
            // packed half index: colb*8192 + (in0>>3)*128 + ci*8 + ((in0>>2)&1)*4
            _Float16* base = dst + (size_t)((col >> 4) * 8192 + (in0 >> 3) * 128 +
                                            (col & 15) * 8 + ((in0 >> 2) & 1) * 4);
            *(half4*)base = h;
        }
    } else {
        int cid = (blockIdx.x - 8704) * 256 + threadIdx.x;
        int kb  = cid >> 11;
        int rem = cid & 2047;
        int db  = rem >> 6;
        int gc  = rem & 63;
        int g   = gc >> 4, c = gc & 15;
        const float* src = Mem + (size_t)(kb * 32 + g * 8) * H + db * 16 + c;
        half8 v;
#pragma unroll
        for (int j = 0; j < 8; ++j) v[j] = (_Float16)src[(size_t)j * H];
        vp[cid] = v;
    }
}

// ---------------------------------------------------------------------------
// K1: both projection GEMMs in one launch (blockIdx.z selects q/k problem).
// out = fp16(X16 @ W^T + b). W in packed layout (see castpack): B-frag load
// wbase[(colb0+nt)*1024 + kk*64 + lq*16 + lr] is a contiguous 1 KB wave-read.
// fp16 A-loads, 32 rows/wave. Grid (64, 8, 2).
// ---------------------------------------------------------------------------
__global__ __launch_bounds__(256, 4)
void proj_kernel(const _Float16* __restrict__ Xq, const _Float16* __restrict__ Wq16,
                 const float* __restrict__ bq, _Float16* __restrict__ oq,
                 const _Float16* __restrict__ Xk, const _Float16* __restrict__ Wk16,
                 const float* __restrict__ bk, _Float16* __restrict__ ok) {
    const _Float16* X16 = blockIdx.z ? Xk : Xq;
    const _Float16* W16 = blockIdx.z ? Wk16 : Wq16;
    const float*    bias = blockIdx.z ? bk : bq;
    _Float16*       out = blockIdx.z ? ok : oq;

    const int lane = threadIdx.x & 63;
    const int wave = threadIdx.x >> 6;
    const int row0 = blockIdx.x * 128 + wave * 32;
    const int col0 = blockIdx.y * 64;
    const int colb0 = col0 >> 4;
    const int lr = lane & 15, lq = lane >> 4;

    floatx4 acc[2][4];
#pragma unroll
    for (int rt = 0; rt < 2; ++rt)
#pragma unroll
        for (int nt = 0; nt < 4; ++nt) { acc[rt][nt][0] = 0.f; acc[rt][nt][1] = 0.f; acc[rt][nt][2] = 0.f; acc[rt][nt][3] = 0.f; }

    const half8* ar0 = (const half8*)(X16 + (size_t)(row0 + lr) * H) + lq;
    const half8* ar1 = (const half8*)(X16 + (size_t)(row0 + 16 + lr) * H) + lq;
    const half8* wbase = (const half8*)W16;

#pragma unroll
    for (int kk = 0; kk < 16; ++kk) {
        half8 a0 = ar0[kk * 4];
        half8 a1 = ar1[kk * 4];
#pragma unroll
        for (int nt = 0; nt < 4; ++nt) {
            half8 bf = wbase[(size_t)(colb0 + nt) * 1024 + kk * 64 + lq * 16 + lr];
            acc[0][nt] = MFMA16(a0, bf, acc[0][nt]);
            acc[1][nt] = MFMA16(a1, bf, acc[1][nt]);
        }
    }
#pragma unroll
    for (int rt = 0; rt < 2; ++rt)
#pragma unroll
        for (int nt = 0; nt < 4; ++nt) {
            int col = col0 + nt * 16 + lr;
            float b = bias[col];
#pragma unroll
            for (int r = 0; r < 4; ++r) {
                int row = row0 + rt * 16 + lq * 4 + r;
                out[(size_t)row * H + col] = (_Float16)(acc[rt][nt][r] + b);
            }
        }
}

// ---------------------------------------------------------------------------
// K2: flash attention, 2-barrier pipelined (R11 schedule, verbatim).
// blockIdx.x = rbk*4+slice; 128 q-rows per block (8 waves x 16-row stripe),
// slice owns 2048 keys as 64 tiles of 32 keys.
// ---------------------------------------------------------------------------
__global__ __launch_bounds__(512, 2)
void flash_kernel(const _Float16* __restrict__ q16, const _Float16* __restrict__ k16,
                  const half8* __restrict__ vp, _Float16* __restrict__ opart,
                  float* __restrict__ mpart, float* __restrict__ lpart) {
    __shared__ half8 klds[2][2048];        // 2 x 32 KB: K tiles, B-frag order
    __shared__ half8 vlds[2][2048];        // 2 x 32 KB: V tiles, packed order
    __shared__ _Float16 plds[2][128 * 36]; // 2 x 9 KB: P, stride 36
    __shared__ float alds[2][128];         // per-row rescale factors, dbuf
    __shared__ float llds[128];            // final per-row l
    __shared__ int flagw[2][8];            // per-wave trigger flag, dbuf

    const int tid = threadIdx.x;
    const int lane = tid & 63;
    const int wave = tid >> 6;
    const int rbk = blockIdx.x >> 2;
    const int slice = blockIdx.x & 3;
    const int row0 = rbk * 128;
    const int lr = lane & 15, lq = lane >> 4;

    // K-DMA source offsets: LDS dst d = tid+i*512 -> (c,kk,g,cc);
    // src = (c*16+cc)*512 + kk*32 + g*8 halves within the 32-key K tile.
    int koff[4];
#pragma unroll
    for (int i = 0; i < 4; ++i) {
        int d = tid + i * 512;
        int c = d >> 10, kk = (d >> 6) & 15, g = (d >> 4) & 3, cc = d & 15;
        koff[i] = c * 8192 + cc * 512 + kk * 32 + g * 8;
    }

    // Q stripe for QK: lane holds q16[row0+wave*16+lr][kk*32+lq*8 ..]
    const half8* qrow = (const half8*)(q16 + (size_t)(row0 + wave * 16 + lr) * H);
    half8 qf[16];
#pragma unroll
    for (int kk = 0; kk < 16; ++kk) qf[kk] = qrow[kk * 4 + lq];

    floatx4 o[8][4];
#pragma unroll
    for (int rb = 0; rb < 8; ++rb)
#pragma unroll
        for (int f = 0; f < 4; ++f) { o[rb][f][0] = 0.f; o[rb][f][1] = 0.f; o[rb][f][2] = 0.f; o[rb][f][3] = 0.f; }
    float m[4], l[4];
#pragma unroll
    for (int r = 0; r < 4; ++r) { m[r] = -1e30f; l[r] = 0.f; }

    // prologue DMA: K(0) -> klds[0], V(0) -> vlds[0], K(1) -> klds[1]
    {
        const int kt0 = slice * 64;
        const _Float16* ksrc0 = k16 + (size_t)kt0 * 16384;
        const half8* vsrc0 = vp + (size_t)kt0 * 2048;
#pragma unroll
        for (int i = 0; i < 4; ++i) dma16(&klds[0][tid + i * 512], ksrc0 + koff[i]);
#pragma unroll
        for (int i = 0; i < 4; ++i) dma16(&vlds[0][tid + i * 512], &vsrc0[tid + i * 512]);
        const _Float16* ksrc1 = k16 + (size_t)(kt0 + 1) * 16384;
#pragma unroll
        for (int i = 0; i < 4; ++i) dma16(&klds[1][tid + i * 512], ksrc1 + koff[i]);
    }

    for (int tt = 0; tt < 64; ++tt) {
        const int b = tt & 1;

        // BAR1: keep 8 newest loads (V(tt), K(tt+1)) in flight; older drained.
        asm volatile("s_waitcnt vmcnt(8) lgkmcnt(0)" ::: "memory");
        __builtin_amdgcn_s_barrier();

        if (tt > 0) {
            const int q1 = b ^ 1;
            // ---- deferred rescale, gated per 16-row chunk (overlapped) ----
#pragma unroll
            for (int rb = 0; rb < 8; ++rb) {
                if (flagw[q1][rb]) {
                    float a0 = alds[q1][rb * 16 + lq * 4 + 0];
                    float a1 = alds[q1][rb * 16 + lq * 4 + 1];
                    float a2 = alds[q1][rb * 16 + lq * 4 + 2];
                    float a3 = alds[q1][rb * 16 + lq * 4 + 3];
#pragma unroll
                    for (int f = 0; f < 4; ++f) {
                        o[rb][f][0] *= a0; o[rb][f][1] *= a1;
                        o[rb][f][2] *= a2; o[rb][f][3] *= a3;
                    }
                }
            }
            // ---- PV(tt-1): overlaps QK ds_reads ----
            __builtin_amdgcn_s_setprio(1);
            half8 vf[4];
#pragma unroll
            for (int f = 0; f < 4; ++f) vf[f] = vlds[q1][(wave * 4 + f) * 64 + lane];
#pragma unroll
            for (int rb = 0; rb < 8; ++rb) {
                half8 pfr = *(const half8*)&plds[q1][(rb * 16 + lr) * 36 + lq * 8];
#pragma unroll
                for (int f = 0; f < 4; ++f) o[rb][f] = MFMA16(pfr, vf[f], o[rb][f]);
            }
            __builtin_amdgcn_s_setprio(0);
        }

        // ---- QK^T(tt): S[16 x 32] per wave, K frags from klds[b] ----
        __builtin_amdgcn_s_setprio(1);
        floatx4 s0 = {0.f, 0.f, 0.f, 0.f}, s1 = {0.f, 0.f, 0.f, 0.f};
#pragma unroll
        for (int kk = 0; kk < 16; ++kk) {
            s0 = MFMA16(qf[kk], klds[b][kk * 64 + lane], s0);
            s1 = MFMA16(qf[kk], klds[b][1024 + kk * 64 + lane], s1);
        }
        __builtin_amdgcn_s_setprio(0);

        // ---- softmax(tt): per-wave trigger (16 rows) ----
        float tm[4]; int trig = 0;
#pragma unroll
        for (int r = 0; r < 4; ++r) {
            tm[r] = fmaxf(s0[r], s1[r]);
            trig |= (tm[r] > m[r] + 10.f) ? 1 : 0;
        }
        const int trigany = __any(trig) ? 1 : 0;
        if (lane == 0) flagw[b][wave] = trigany;
        if (trigany) {
            float al[4];
#pragma unroll
            for (int r = 0; r < 4; ++r) {
                float mx = tm[r];
                mx = fmaxf(mx, __shfl_xor(mx, 1));
                mx = fmaxf(mx, __shfl_xor(mx, 2));
                mx = fmaxf(mx, __shfl_xor(mx, 4));
                mx = fmaxf(mx, __shfl_xor(mx, 8));
                float mn = (mx > m[r] + 10.f) ? mx : m[r];
                al[r] = __expf(m[r] - mn);
                m[r] = mn;
                l[r] *= al[r];
            }
            if (lr == 0) {
#pragma unroll
                for (int r = 0; r < 4; ++r) alds[b][wave * 16 + lq * 4 + r] = al[r];
            }
        }

        // ---- exp, l accumulate, P -> plds[b] (overlapped; dbuf) ----
#pragma unroll
        for (int r = 0; r < 4; ++r) {
            float p0 = __expf(s0[r] - m[r]);
            float p1 = __expf(s1[r] - m[r]);
            l[r] += p0 + p1;
            plds[b][(wave * 16 + lq * 4 + r) * 36 + lr]      = (_Float16)p0;
            plds[b][(wave * 16 + lq * 4 + r) * 36 + 16 + lr] = (_Float16)p1;
        }

        // BAR2: all waves' klds[b]/vlds[b^1] reads consumed; LDS writes landed.
        asm volatile("s_waitcnt lgkmcnt(0)" ::: "memory");
        __builtin_amdgcn_s_barrier();

        // ---- issue DMA: V(tt+1) -> vlds[(tt+1)&1], K(tt+2) -> klds[b] ----
        // Tail-clamped (dead-buffer writes) to keep vmcnt count uniform at 8.
        {
            int vt = tt + 1; if (vt > 63) vt = 63;
            int kt2 = tt + 2; if (kt2 > 63) kt2 = 63;
            const half8* vsrc = vp + (size_t)(slice * 64 + vt) * 2048;
#pragma unroll
            for (int i = 0; i < 4; ++i) dma16(&vlds[(tt + 1) & 1][tid + i * 512], &vsrc[tid + i * 512]);
            const _Float16* ksrc = k16 + (size_t)(slice * 64 + kt2) * 16384;
#pragma unroll
            for (int i = 0; i < 4; ++i) dma16(&klds[b][tid + i * 512], ksrc + koff[i]);
        }
    }

    // ---- epilogue: rescale(63) + PV(63); all P/alds/flagw written pre-BAR2(63)
    asm volatile("s_waitcnt lgkmcnt(0)" ::: "memory");
    {
#pragma unroll
        for (int rb = 0; rb < 8; ++rb) {
            if (flagw[1][rb]) {
                float a0 = alds[1][rb * 16 + lq * 4 + 0];
                float a1 = alds[1][rb * 16 + lq * 4 + 1];
                float a2 = alds[1][rb * 16 + lq * 4 + 2];
                float a3 = alds[1][rb * 16 + lq * 4 + 3];
#pragma unroll
                for (int f = 0; f < 4; ++f) {
                    o[rb][f][0] *= a0; o[rb][f][1] *= a1;
                    o[rb][f][2] *= a2; o[rb][f][3] *= a3;
                }
            }
        }
        __builtin_amdgcn_s_setprio(1);
        half8 vf[4];
#pragma unroll
        for (int f = 0; f < 4; ++f) vf[f] = vlds[1][(wave * 4 + f) * 64 + lane];
#pragma unroll
        for (int rb = 0; rb < 8; ++rb) {
            half8 pfr = *(const half8*)&plds[1][(rb * 16 + lr) * 36 + lq * 8];
#pragma unroll
            for (int f = 0; f < 4; ++f) o[rb][f] = MFMA16(pfr, vf[f], o[rb][f]);
        }
        __builtin_amdgcn_s_setprio(0);
    }

    // ---- final l reduction over the 16 lr lanes ----
#pragma unroll
    for (int r = 0; r < 4; ++r) {
        float lv = l[r];
        lv += __shfl_xor(lv, 1); lv += __shfl_xor(lv, 2);
        lv += __shfl_xor(lv, 4); lv += __shfl_xor(lv, 8);
        l[r] = lv;
    }
    if (lr == 0) {
#pragma unroll
        for (int r = 0; r < 4; ++r) {
            int row = wave * 16 + lq * 4 + r;
            llds[row] = l[r];
            mpart[slice * NROWS + row0 + row] = m[r];
            lpart[slice * NROWS + row0 + row] = l[r];
        }
    }
    __syncthreads();

    // ---- normalized O store (fp16); wave owns d-slice [wave*64, +64) ----
    _Float16* ob = opart + (size_t)slice * NROWS * H;
#pragma unroll
    for (int rb = 0; rb < 8; ++rb) {
#pragma unroll
        for (int rr = 0; rr < 4; ++rr) {
            float linv = 1.0f / llds[rb * 16 + lq * 4 + rr];
            size_t row = row0 + rb * 16 + lq * 4 + rr;
#pragma unroll
            for (int f = 0; f < 4; ++f)
                ob[row * H + wave * 64 + f * 16 + lr] = (_Float16)(o[rb][f][rr] * linv);
        }
    }
}

// ---------------------------------------------------------------------------
// K3: merge normalized slice partials, 4 outputs/thread, vectorized.
// ---------------------------------------------------------------------------
__global__ void merge_kernel(const _Float16* __restrict__ opart, const float* __restrict__ mpart,
                             const float* __restrict__ lpart, const float* __restrict__ F,
                             float* __restrict__ out) {
    int gid = blockIdx.x * 256 + threadIdx.x;
    size_t idx4 = (size_t)gid * 4;
    int row = (int)(idx4 >> 9);
    float m0 = mpart[row], m1 = mpart[NROWS + row], m2 = mpart[2 * NROWS + row], m3 = mpart[3 * NROWS + row];
    float ms = fmaxf(fmaxf(m0, m1), fmaxf(m2, m3));
    float w0 = __expf(m0 - ms) * lpart[row];
    float w1 = __expf(m1 - ms) * lpart[NROWS + row];
    float w2 = __expf(m2 - ms) * lpart[2 * NROWS + row];
    float w3 = __expf(m3 - ms) * lpart[3 * NROWS + row];
    float rdenom = 1.0f / (w0 + w1 + w2 + w3);
    size_t stride = (size_t)NROWS * H;
    half4 o0 = *(const half4*)&opart[idx4];
    half4 o1 = *(const half4*)&opart[stride + idx4];
    half4 o2 = *(const half4*)&opart[2 * stride + idx4];
    half4 o3 = *(const half4*)&opart[3 * stride + idx4];
    float4 Fv = *(const float4*)&F[idx4];
    float4 res;
    res.x = 0.5f * Fv.x + 0.5f * ((w0 * (float)o0[0] + w1 * (float)o1[0] + w2 * (float)o2[0] + w3 * (float)o3[0]) * rdenom);
    res.y = 0.5f * Fv.y + 0.5f * ((w0 * (float)o0[1] + w1 * (float)o1[1] + w2 * (float)o2[1] + w3 * (float)o3[1]) * rdenom);
    res.z = 0.5f * Fv.z + 0.5f * ((w0 * (float)o0[2] + w1 * (float)o1[2] + w2 * (float)o2[2] + w3 * (float)o3[2]) * rdenom);
    res.w = 0.5f * Fv.w + 0.5f * ((w0 * (float)o0[3] + w1 * (float)o1[3] + w2 * (float)o2[3] + w3 * (float)o3[3]) * rdenom);
    *(float4*)&out[idx4] = res;
}

// ---------------------------------------------------------------------------
// Workspace (~58 MB):
//   [ 0M,  8M) q16   [ 8M, 16M) k16   [16M, 24M) vp   [24M, 56M) opart fp16
//   f16F aliases opart[24M,32M), m16 aliases opart[32M,40M) — both dead
//   before flash_kernel writes opart (stream-ordered).
//   [56M,+128K) mpart  [+128K] lpart  [57M,+1M) wq16/wk16 (packed layout)
// ---------------------------------------------------------------------------
extern "C" void kernel_launch(void* const* d_in, const int* in_sizes, int n_in,
                              void* d_out, int out_size, void* d_ws, size_t ws_size,
                              hipStream_t stream) {
    const float* F   = (const float*)d_in[0];
    const float* Mem = (const float*)d_in[1];
    const float* Wq  = (const float*)d_in[2];
    const float* bq  = (const float*)d_in[3];
    const float* Wk  = (const float*)d_in[4];
    const float* bk  = (const float*)d_in[5];
    float* out = (float*)d_out;

    char* ws = (char*)d_ws;
    _Float16* q16   = (_Float16*)(ws);
    _Float16* k16   = (_Float16*)(ws + (8ull << 20));
    half8*    vp    = (half8*)(ws + (16ull << 20));
    _Float16* opart = (_Float16*)(ws + (24ull << 20));
    _Float16* f16F  = (_Float16*)(ws + (24ull << 20));   // aliases opart slice 0
    _Float16* m16   = (_Float16*)(ws + (32ull << 20));   // aliases opart slice 1
    float*    mpart = (float*)(ws + (56ull << 20));
    float*    lpart = (float*)(ws + (56ull << 20) + (128ull << 10));
    _Float16* wq16  = (_Float16*)(ws + (57ull << 20));
    _Float16* wk16  = (_Float16*)(ws + (57ull << 20) + (512ull << 10));

    castpack_kernel<<<10752, 256, 0, stream>>>(F, Mem, Wq, Wk, f16F, m16, wq16, wk16, vp);
    proj_kernel<<<dim3(64, 8, 2), 256, 0, stream>>>(f16F, wq16, bq, q16, m16, wk16, bk, k16);
    flash_kernel<<<256, 512, 0, stream>>>(q16, k16, vp, opart, mpart, lpart);
    merge_kernel<<<4096, 256, 0, stream>>>(opart, mpart, lpart, F, out);
}

// Round 14
// 305.301 us; speedup vs baseline: 1.1018x; 1.0294x over previous
//
#include <hip/hip_runtime.h>

// ---------------------------------------------------------------------------
// out = 0.5*F + 0.5*softmax((F Wq^T)(M Wk^T)^T) M ;  N=M=8192, H=512, fp32.
// R17: R16 + packed A-operand. castpack's cast path now runs 16-row tiles
// through an LDS transpose (coalesced fp32 reads -> LDS, padded stride 520
// -> 2-way-conflict-free packed reads -> contiguous 16B/lane writes) into
// xpk[rowb][j=kk*4+lq][ri=row&15] (half8 units), so proj's A-frag wave-load
// is one contiguous 1 KB block (was a 16x64B gather at 1 KB stride), same
// as R16 did for B. f16pk/m16pk are consumed ONLY by proj (packv reads Mem
// fp32; flash reads q16/k16), so the re-layout is safe.
// Flash = R11 2-barrier schedule, byte-identical (212.6 µs, 4x-confirmed).
// ---------------------------------------------------------------------------

typedef _Float16 half8 __attribute__((ext_vector_type(8)));
typedef _Float16 half4 __attribute__((ext_vector_type(4)));
typedef float floatx4 __attribute__((ext_vector_type(4)));

#define MFMA16(a, b, c) __builtin_amdgcn_mfma_f32_16x16x32_f16((a), (b), (c), 0, 0, 0)

static constexpr int H = 512;
static constexpr int NROWS = 8192;

__device__ __forceinline__ void dma16(half8* lds_dst, const void* g_src) {
    __builtin_amdgcn_global_load_lds(
        (const __attribute__((address_space(1))) unsigned int*)g_src,
        (__attribute__((address_space(3))) unsigned int*)lds_dst,
        16, 0, 0);
}

// ---------------------------------------------------------------------------
// K0: fused cast + pack, grid 3584.
// Blocks [0,1024): X-pack. Tile = 16 rows x 512 cols of [F;Mem] fp32.
//   Coalesced float4 reads -> fp16 LDS tile (stride 520 halves, pad kills
//   bank conflicts) -> packed write: unit (rowb, u=j*16+ri) holds
//   X[rowb*16+ri][j*8 .. +8]; consecutive threads write consecutive units.
// Blocks [1024,1536): W cast+pack (R16 layout, coalesced enough — W is tiny).
// Blocks [1536,3584): pack V fp32->fp16 into MFMA B-frag order (unchanged):
//   vp[kb*2048 + db*64 + g*16 + c][j] = Mem[(kb*32+g*8+j)*512 + db*16 + c]
// ---------------------------------------------------------------------------
__global__ void castpack_kernel(const float* __restrict__ F, const float* __restrict__ Mem,
                                const float* __restrict__ wq, const float* __restrict__ wk,
                                _Float16* __restrict__ f16pk, _Float16* __restrict__ m16pk,
                                _Float16* __restrict__ wq16, _Float16* __restrict__ wk16,
                                half8* __restrict__ vp) {
    if (blockIdx.x < 1024) {
        __shared__ _Float16 xl[16 * 520];       // 16.3 KB, +8-half row pad
        const int t = threadIdx.x;
        const int rowt0 = blockIdx.x * 16;      // row in concatenated [F;Mem]
        const float* src = (rowt0 < 8192) ? (F + (size_t)rowt0 * 512)
                                          : (Mem + (size_t)(rowt0 - 8192) * 512);
        _Float16* dstpk = (rowt0 < 8192) ? f16pk : m16pk;
        const int rowb = blockIdx.x & 511;      // 16-row block index in tensor
#pragma unroll
        for (int i = 0; i < 8; ++i) {
            int li = t + i * 256;               // float4 index in tile [0,2048)
            int r  = li >> 7;                   // 128 float4 per row
            int c4 = (li & 127) * 4;
            float4 v = *(const float4*)&src[(size_t)r * 512 + c4];
            half4 h;
            h[0] = (_Float16)v.x; h[1] = (_Float16)v.y;
            h[2] = (_Float16)v.z; h[3] = (_Float16)v.w;
            *(half4*)&xl[r * 520 + c4] = h;
        }
        __syncthreads();
        half8* dst = (half8*)dstpk;
#pragma unroll
        for (int i = 0; i < 4; ++i) {
            int u = t + i * 256;                // unit index [0,1024)
            int j = u >> 4, ri = u & 15;
            half8 v = *(const half8*)&xl[ri * 520 + j * 8];
            dst[(size_t)rowb * 1024 + u] = v;
        }
    } else if (blockIdx.x < 1536) {
        size_t i4 = (size_t)((blockIdx.x - 1024) * 256 + threadIdx.x) * 4;  // [0, 524288)
        const float* src; _Float16* dst; size_t off;
        if (i4 < 262144ull) { src = wq; dst = wq16; off = i4; }
        else                { src = wk; dst = wk16; off = i4 - 262144ull; }
        int col = (int)(off >> 9);              // W row-major [col][in], 512 wide
        int in0 = (int)(off & 511);             // multiple of 4
        float4 v = *(const float4*)&src[off];
        half4 h;
        h[0] = (_Float16)v.x; h[1] = (_Float16)v.y;
        h[2] = (_Float16)v.z; h[3] = (_Float16)v.w;
        _Float16* base = dst + (size_t)((col >> 4) * 8192 + (in0 >> 3) * 128 +
                                        (col & 15) * 8 + ((in0 >> 2) & 1) * 4);
        *(half4*)base = h;
    } else {
        int cid = (blockIdx.x - 1536) * 256 + threadIdx.x;
        int kb  = cid >> 11;
        int rem = cid & 2047;
        int db  = rem >> 6;
        int gc  = rem & 63;
        int g   = gc >> 4, c = gc & 15;
        const float* src = Mem + (size_t)(kb * 32 + g * 8) * H + db * 16 + c;
        half8 v;
#pragma unroll
        for (int j = 0; j < 8; ++j) v[j] = (_Float16)src[(size_t)j * H];
        vp[cid] = v;
    }
}

// ---------------------------------------------------------------------------
// K1: both projection GEMMs in one launch (blockIdx.z selects q/k problem).
// out = fp16(X @ W^T + b). X and W both in packed layouts: A-frag load
// xb[rowb*1024 + kk*64 + lq*16 + lr] and B-frag load
// wbase[(colb0+nt)*1024 + kk*64 + lq*16 + lr] are contiguous 1 KB wave-reads.
// 32 rows/wave. Grid (64, 8, 2).
// ---------------------------------------------------------------------------
__global__ __launch_bounds__(256, 4)
void proj_kernel(const _Float16* __restrict__ Xq, const _Float16* __restrict__ Wq16,
                 const float* __restrict__ bq, _Float16* __restrict__ oq,
                 const _Float16* __restrict__ Xk, const _Float16* __restrict__ Wk16,
                 const float* __restrict__ bk, _Float16* __restrict__ ok) {
    const _Float16* X16 = blockIdx.z ? Xk : Xq;
    const _Float16* W16 = blockIdx.z ? Wk16 : Wq16;
    const float*    bias = blockIdx.z ? bk : bq;
    _Float16*       out = blockIdx.z ? ok : oq;

    const int lane = threadIdx.x & 63;
    const int wave = threadIdx.x >> 6;
    const int row0 = blockIdx.x * 128 + wave * 32;
    const int rowb0 = blockIdx.x * 8 + wave * 2;   // row0 >> 4
    const int col0 = blockIdx.y * 64;
    const int colb0 = col0 >> 4;
    const int lr = lane & 15, lq = lane >> 4;

    floatx4 acc[2][4];
#pragma unroll
    for (int rt = 0; rt < 2; ++rt)
#pragma unroll
        for (int nt = 0; nt < 4; ++nt) { acc[rt][nt][0] = 0.f; acc[rt][nt][1] = 0.f; acc[rt][nt][2] = 0.f; acc[rt][nt][3] = 0.f; }

    const half8* xb = (const half8*)X16;
    const half8* wbase = (const half8*)W16;

#pragma unroll
    for (int kk = 0; kk < 16; ++kk) {
        half8 a0 = xb[(size_t)rowb0 * 1024 + kk * 64 + lq * 16 + lr];
        half8 a1 = xb[(size_t)(rowb0 + 1) * 1024 + kk * 64 + lq * 16 + lr];
#pragma unroll
        for (int nt = 0; nt < 4; ++nt) {
            half8 bf = wbase[(size_t)(colb0 + nt) * 1024 + kk * 64 + lq * 16 + lr];
            acc[0][nt] = MFMA16(a0, bf, acc[0][nt]);
            acc[1][nt] = MFMA16(a1, bf, acc[1][nt]);
        }
    }
#pragma unroll
    for (int rt = 0; rt < 2; ++rt)
#pragma unroll
        for (int nt = 0; nt < 4; ++nt) {
            int col = col0 + nt * 16 + lr;
            float b = bias[col];
#pragma unroll
            for (int r = 0; r < 4; ++r) {
                int row = row0 + rt * 16 + lq * 4 + r;
                out[(size_t)row * H + col] = (_Float16)(acc[rt][nt][r] + b);
            }
        }
}

// ---------------------------------------------------------------------------
// K2: flash attention, 2-barrier pipelined (R11 schedule, verbatim).
// blockIdx.x = rbk*4+slice; 128 q-rows per block (8 waves x 16-row stripe),
// slice owns 2048 keys as 64 tiles of 32 keys.
// ---------------------------------------------------------------------------
__global__ __launch_bounds__(512, 2)
void flash_kernel(const _Float16* __restrict__ q16, const _Float16* __restrict__ k16,
                  const half8* __restrict__ vp, _Float16* __restrict__ opart,
                  float* __restrict__ mpart, float* __restrict__ lpart) {
    __shared__ half8 klds[2][2048];        // 2 x 32 KB: K tiles, B-frag order
    __shared__ half8 vlds[2][2048];        // 2 x 32 KB: V tiles, packed order
    __shared__ _Float16 plds[2][128 * 36]; // 2 x 9 KB: P, stride 36
    __shared__ float alds[2][128];         // per-row rescale factors, dbuf
    __shared__ float llds[128];            // final per-row l
    __shared__ int flagw[2][8];            // per-wave trigger flag, dbuf

    const int tid = threadIdx.x;
    const int lane = tid & 63;
    const int wave = tid >> 6;
    const int rbk = blockIdx.x >> 2;
    const int slice = blockIdx.x & 3;
    const int row0 = rbk * 128;
    const int lr = lane & 15, lq = lane >> 4;

    // K-DMA source offsets: LDS dst d = tid+i*512 -> (c,kk,g,cc);
    // src = (c*16+cc)*512 + kk*32 + g*8 halves within the 32-key K tile.
    int koff[4];
#pragma unroll
    for (int i = 0; i < 4; ++i) {
        int d = tid + i * 512;
        int c = d >> 10, kk = (d >> 6) & 15, g = (d >> 4) & 3, cc = d & 15;
        koff[i] = c * 8192 + cc * 512 + kk * 32 + g * 8;
    }

    // Q stripe for QK: lane holds q16[row0+wave*16+lr][kk*32+lq*8 ..]
    const half8* qrow = (const half8*)(q16 + (size_t)(row0 + wave * 16 + lr) * H);
    half8 qf[16];
#pragma unroll
    for (int kk = 0; kk < 16; ++kk) qf[kk] = qrow[kk * 4 + lq];

    floatx4 o[8][4];
#pragma unroll
    for (int rb = 0; rb < 8; ++rb)
#pragma unroll
        for (int f = 0; f < 4; ++f) { o[rb][f][0] = 0.f; o[rb][f][1] = 0.f; o[rb][f][2] = 0.f; o[rb][f][3] = 0.f; }
    float m[4], l[4];
#pragma unroll
    for (int r = 0; r < 4; ++r) { m[r] = -1e30f; l[r] = 0.f; }

    // prologue DMA: K(0) -> klds[0], V(0) -> vlds[0], K(1) -> klds[1]
    {
        const int kt0 = slice * 64;
        const _Float16* ksrc0 = k16 + (size_t)kt0 * 16384;
        const half8* vsrc0 = vp + (size_t)kt0 * 2048;
#pragma unroll
        for (int i = 0; i < 4; ++i) dma16(&klds[0][tid + i * 512], ksrc0 + koff[i]);
#pragma unroll
        for (int i = 0; i < 4; ++i) dma16(&vlds[0][tid + i * 512], &vsrc0[tid + i * 512]);
        const _Float16* ksrc1 = k16 + (size_t)(kt0 + 1) * 16384;
#pragma unroll
        for (int i = 0; i < 4; ++i) dma16(&klds[1][tid + i * 512], ksrc1 + koff[i]);
    }

    for (int tt = 0; tt < 64; ++tt) {
        const int b = tt & 1;

        // BAR1: keep 8 newest loads (V(tt), K(tt+1)) in flight; older drained.
        asm volatile("s_waitcnt vmcnt(8) lgkmcnt(0)" ::: "memory");
        __builtin_amdgcn_s_barrier();

        if (tt > 0) {
            const int q1 = b ^ 1;
            // ---- deferred rescale, gated per 16-row chunk (overlapped) ----
#pragma unroll
            for (int rb = 0; rb < 8; ++rb) {
                if (flagw[q1][rb]) {
                    float a0 = alds[q1][rb * 16 + lq * 4 + 0];
                    float a1 = alds[q1][rb * 16 + lq * 4 + 1];
                    float a2 = alds[q1][rb * 16 + lq * 4 + 2];
                    float a3 = alds[q1][rb * 16 + lq * 4 + 3];
#pragma unroll
                    for (int f = 0; f < 4; ++f) {
                        o[rb][f][0] *= a0; o[rb][f][1] *= a1;
                        o[rb][f][2] *= a2; o[rb][f][3] *= a3;
                    }
                }
            }
            // ---- PV(tt-1): overlaps QK ds_reads ----
            __builtin_amdgcn_s_setprio(1);
            half8 vf[4];
#pragma unroll
            for (int f = 0; f < 4; ++f) vf[f] = vlds[q1][(wave * 4 + f) * 64 + lane];
#pragma unroll
            for (int rb = 0; rb < 8; ++rb) {
                half8 pfr = *(const half8*)&plds[q1][(rb * 16 + lr) * 36 + lq * 8];
#pragma unroll
                for (int f = 0; f < 4; ++f) o[rb][f] = MFMA16(pfr, vf[f], o[rb][f]);
            }
            __builtin_amdgcn_s_setprio(0);
        }

        // ---- QK^T(tt): S[16 x 32] per wave, K frags from klds[b] ----
        __builtin_amdgcn_s_setprio(1);
        floatx4 s0 = {0.f, 0.f, 0.f, 0.f}, s1 = {0.f, 0.f, 0.f, 0.f};
#pragma unroll
        for (int kk = 0; kk < 16; ++kk) {
            s0 = MFMA16(qf[kk], klds[b][kk * 64 + lane], s0);
            s1 = MFMA16(qf[kk], klds[b][1024 + kk * 64 + lane], s1);
        }
        __builtin_amdgcn_s_setprio(0);

        // ---- softmax(tt): per-wave trigger (16 rows) ----
        float tm[4]; int trig = 0;
#pragma unroll
        for (int r = 0; r < 4; ++r) {
            tm[r] = fmaxf(s0[r], s1[r]);
            trig |= (tm[r] > m[r] + 10.f) ? 1 : 0;
        }
        const int trigany = __any(trig) ? 1 : 0;
        if (lane == 0) flagw[b][wave] = trigany;
        if (trigany) {
            float al[4];
#pragma unroll
            for (int r = 0; r < 4; ++r) {
                float mx = tm[r];
                mx = fmaxf(mx, __shfl_xor(mx, 1));
                mx = fmaxf(mx, __shfl_xor(mx, 2));
                mx = fmaxf(mx, __shfl_xor(mx, 4));
                mx = fmaxf(mx, __shfl_xor(mx, 8));
                float mn = (mx > m[r] + 10.f) ? mx : m[r];
                al[r] = __expf(m[r] - mn);
                m[r] = mn;
                l[r] *= al[r];
            }
            if (lr == 0) {
#pragma unroll
                for (int r = 0; r < 4; ++r) alds[b][wave * 16 + lq * 4 + r] = al[r];
            }
        }

        // ---- exp, l accumulate, P -> plds[b] (overlapped; dbuf) ----
#pragma unroll
        for (int r = 0; r < 4; ++r) {
            float p0 = __expf(s0[r] - m[r]);
            float p1 = __expf(s1[r] - m[r]);
            l[r] += p0 + p1;
            plds[b][(wave * 16 + lq * 4 + r) * 36 + lr]      = (_Float16)p0;
            plds[b][(wave * 16 + lq * 4 + r) * 36 + 16 + lr] = (_Float16)p1;
        }

        // BAR2: all waves' klds[b]/vlds[b^1] reads consumed; LDS writes landed.
        asm volatile("s_waitcnt lgkmcnt(0)" ::: "memory");
        __builtin_amdgcn_s_barrier();

        // ---- issue DMA: V(tt+1) -> vlds[(tt+1)&1], K(tt+2) -> klds[b] ----
        // Tail-clamped (dead-buffer writes) to keep vmcnt count uniform at 8.
        {
            int vt = tt + 1; if (vt > 63) vt = 63;
            int kt2 = tt + 2; if (kt2 > 63) kt2 = 63;
            const half8* vsrc = vp + (size_t)(slice * 64 + vt) * 2048;
#pragma unroll
            for (int i = 0; i < 4; ++i) dma16(&vlds[(tt + 1) & 1][tid + i * 512], &vsrc[tid + i * 512]);
            const _Float16* ksrc = k16 + (size_t)(slice * 64 + kt2) * 16384;
#pragma unroll
            for (int i = 0; i < 4; ++i) dma16(&klds[b][tid + i * 512], ksrc + koff[i]);
        }
    }

    // ---- epilogue: rescale(63) + PV(63); all P/alds/flagw written pre-BAR2(63)
    asm volatile("s_waitcnt lgkmcnt(0)" ::: "memory");
    {
#pragma unroll
        for (int rb = 0; rb < 8; ++rb) {
            if (flagw[1][rb]) {
                float a0 = alds[1][rb * 16 + lq * 4 + 0];
                float a1 = alds[1][rb * 16 + lq * 4 + 1];
                float a2 = alds[1][rb * 16 + lq * 4 + 2];
                float a3 = alds[1][rb * 16 + lq * 4 + 3];
#pragma unroll
                for (int f = 0; f < 4; ++f) {
                    o[rb][f][0] *= a0; o[rb][f][1] *= a1;
                    o[rb][f][2] *= a2; o[rb][f][3] *= a3;
                }
            }
        }
        __builtin_amdgcn_s_setprio(1);
        half8 vf[4];
#pragma unroll
        for (int f = 0; f < 4; ++f) vf[f] = vlds[1][(wave * 4 + f) * 64 + lane];
#pragma unroll
        for (int rb = 0; rb < 8; ++rb) {
            half8 pfr = *(const half8*)&plds[1][(rb * 16 + lr) * 36 + lq * 8];
#pragma unroll
            for (int f = 0; f < 4; ++f) o[rb][f] = MFMA16(pfr, vf[f], o[rb][f]);
        }
        __builtin_amdgcn_s_setprio(0);
    }

    // ---- final l reduction over the 16 lr lanes ----
#pragma unroll
    for (int r = 0; r < 4; ++r) {
        float lv = l[r];
        lv += __shfl_xor(lv, 1); lv += __shfl_xor(lv, 2);
        lv += __shfl_xor(lv, 4); lv += __shfl_xor(lv, 8);
        l[r] = lv;
    }
    if (lr == 0) {
#pragma unroll
        for (int r = 0; r < 4; ++r) {
            int row = wave * 16 + lq * 4 + r;
            llds[row] = l[r];
            mpart[slice * NROWS + row0 + row] = m[r];
            lpart[slice * NROWS + row0 + row] = l[r];
        }
    }
    __syncthreads();

    // ---- normalized O store (fp16); wave owns d-slice [wave*64, +64) ----
    _Float16* ob = opart + (size_t)slice * NROWS * H;
#pragma unroll
    for (int rb = 0; rb < 8; ++rb) {
#pragma unroll
        for (int rr = 0; rr < 4; ++rr) {
            float linv = 1.0f / llds[rb * 16 + lq * 4 + rr];
            size_t row = row0 + rb * 16 + lq * 4 + rr;
#pragma unroll
            for (int f = 0; f < 4; ++f)
                ob[row * H + wave * 64 + f * 16 + lr] = (_Float16)(o[rb][f][rr] * linv);
        }
    }
}

// ---------------------------------------------------------------------------
// K3: merge normalized slice partials, 4 outputs/thread, vectorized.
// ---------------------------------------------------------------------------
__global__ void merge_kernel(const _Float16* __restrict__ opart, const float* __restrict__ mpart,
                             const float* __restrict__ lpart, const float* __restrict__ F,
                             float* __restrict__ out) {
    int gid = blockIdx.x * 256 + threadIdx.x;
    size_t idx4 = (size_t)gid * 4;
    int row = (int)(idx4 >> 9);
    float m0 = mpart[row], m1 = mpart[NROWS + row], m2 = mpart[2 * NROWS + row], m3 = mpart[3 * NROWS + row];
    float ms = fmaxf(fmaxf(m0, m1), fmaxf(m2, m3));
    float w0 = __expf(m0 - ms) * lpart[row];
    float w1 = __expf(m1 - ms) * lpart[NROWS + row];
    float w2 = __expf(m2 - ms) * lpart[2 * NROWS + row];
    float w3 = __expf(m3 - ms) * lpart[3 * NROWS + row];
    float rdenom = 1.0f / (w0 + w1 + w2 + w3);
    size_t stride = (size_t)NROWS * H;
    half4 o0 = *(const half4*)&opart[idx4];
    half4 o1 = *(const half4*)&opart[stride + idx4];
    half4 o2 = *(const half4*)&opart[2 * stride + idx4];
    half4 o3 = *(const half4*)&opart[3 * stride + idx4];
    float4 Fv = *(const float4*)&F[idx4];
    float4 res;
    res.x = 0.5f * Fv.x + 0.5f * ((w0 * (float)o0[0] + w1 * (float)o1[0] + w2 * (float)o2[0] + w3 * (float)o3[0]) * rdenom);
    res.y = 0.5f * Fv.y + 0.5f * ((w0 * (float)o0[1] + w1 * (float)o1[1] + w2 * (float)o2[1] + w3 * (float)o3[1]) * rdenom);
    res.z = 0.5f * Fv.z + 0.5f * ((w0 * (float)o0[2] + w1 * (float)o1[2] + w2 * (float)o2[2] + w3 * (float)o3[2]) * rdenom);
    res.w = 0.5f * Fv.w + 0.5f * ((w0 * (float)o0[3] + w1 * (float)o1[3] + w2 * (float)o2[3] + w3 * (float)o3[3]) * rdenom);
    *(float4*)&out[idx4] = res;
}

// ---------------------------------------------------------------------------
// Workspace (~58 MB):
//   [ 0M,  8M) q16   [ 8M, 16M) k16   [16M, 24M) vp   [24M, 56M) opart fp16
//   f16pk aliases opart[24M,32M), m16pk aliases opart[32M,40M) — both dead
//   before flash_kernel writes opart (stream-ordered).
//   [56M,+128K) mpart  [+128K] lpart  [57M,+1M) wq16/wk16 (packed layout)
// ---------------------------------------------------------------------------
extern "C" void kernel_launch(void* const* d_in, const int* in_sizes, int n_in,
                              void* d_out, int out_size, void* d_ws, size_t ws_size,
                              hipStream_t stream) {
    const float* F   = (const float*)d_in[0];
    const float* Mem = (const float*)d_in[1];
    const float* Wq  = (const float*)d_in[2];
    const float* bq  = (const float*)d_in[3];
    const float* Wk  = (const float*)d_in[4];
    const float* bk  = (const float*)d_in[5];
    float* out = (float*)d_out;

    char* ws = (char*)d_ws;
    _Float16* q16   = (_Float16*)(ws);
    _Float16* k16   = (_Float16*)(ws + (8ull << 20));
    half8*    vp    = (half8*)(ws + (16ull << 20));
    _Float16* opart = (_Float16*)(ws + (24ull << 20));
    _Float16* f16pk = (_Float16*)(ws + (24ull << 20));   // aliases opart slice 0
    _Float16* m16pk = (_Float16*)(ws + (32ull << 20));   // aliases opart slice 1
    float*    mpart = (float*)(ws + (56ull << 20));
    float*    lpart = (float*)(ws + (56ull << 20) + (128ull << 10));
    _Float16* wq16  = (_Float16*)(ws + (57ull << 20));
    _Float16* wk16  = (_Float16*)(ws + (57ull << 20) + (512ull << 10));

    castpack_kernel<<<3584, 256, 0, stream>>>(F, Mem, Wq, Wk, f16pk, m16pk, wq16, wk16, vp);
    proj_kernel<<<dim3(64, 8, 2), 256, 0, stream>>>(f16pk, wq16, bq, q16, m16pk, wk16, bk, k16);
    flash_kernel<<<256, 512, 0, stream>>>(q16, k16, vp, opart, mpart, lpart);
    merge_kernel<<<4096, 256, 0, stream>>>(opart, mpart, lpart, F, out);
}

// Round 15
// 299.472 us; speedup vs baseline: 1.1232x; 1.0195x over previous
//
#include <hip/hip_runtime.h>

// ---------------------------------------------------------------------------
// out = 0.5*F + 0.5*softmax((F Wq^T)(M Wk^T)^T) M ;  N=M=8192, H=512, fp32.
// R18: R17 + proj LDS-transpose epilogue. proj stages its C-tile (128x64
// fp16) in LDS, then writes: Q row-major (128B segments) and K directly in
// the klds B-frag order kpk[kt*2048 + c*1024 + kk*64 + g*16 + cc] (1KB
// contiguous per wave). Flash's K-DMA source becomes perfectly linear
// (ksrc + tid + i*512) — identical destination data (kpk layout == old koff
// decode, index-verified), identical DMA counts and vmcnt ledger; kills the
// 16B@1KB-stride gather (4x L2-transaction amplification on the K stream).
// Flash schedule = R11 2-barrier, otherwise verbatim (212.6 µs, 5x-confirmed).
// ---------------------------------------------------------------------------

typedef _Float16 half8 __attribute__((ext_vector_type(8)));
typedef _Float16 half4 __attribute__((ext_vector_type(4)));
typedef float floatx4 __attribute__((ext_vector_type(4)));

#define MFMA16(a, b, c) __builtin_amdgcn_mfma_f32_16x16x32_f16((a), (b), (c), 0, 0, 0)

static constexpr int H = 512;
static constexpr int NROWS = 8192;

__device__ __forceinline__ void dma16(half8* lds_dst, const void* g_src) {
    __builtin_amdgcn_global_load_lds(
        (const __attribute__((address_space(1))) unsigned int*)g_src,
        (__attribute__((address_space(3))) unsigned int*)lds_dst,
        16, 0, 0);
}

// ---------------------------------------------------------------------------
// K0: fused cast + pack, grid 3584 (unchanged from R17).
// Blocks [0,1024): X-pack via LDS transpose -> xpk[rowb][j][ri] half8 units.
// Blocks [1024,1536): W cast+pack (R16 layout).
// Blocks [1536,3584): pack V fp32->fp16 into MFMA B-frag order:
//   vp[kb*2048 + db*64 + g*16 + c][j] = Mem[(kb*32+g*8+j)*512 + db*16 + c]
// ---------------------------------------------------------------------------
__global__ void castpack_kernel(const float* __restrict__ F, const float* __restrict__ Mem,
                                const float* __restrict__ wq, const float* __restrict__ wk,
                                _Float16* __restrict__ f16pk, _Float16* __restrict__ m16pk,
                                _Float16* __restrict__ wq16, _Float16* __restrict__ wk16,
                                half8* __restrict__ vp) {
    if (blockIdx.x < 1024) {
        __shared__ _Float16 xl[16 * 520];       // 16.3 KB, +8-half row pad
        const int t = threadIdx.x;
        const int rowt0 = blockIdx.x * 16;      // row in concatenated [F;Mem]
        const float* src = (rowt0 < 8192) ? (F + (size_t)rowt0 * 512)
                                          : (Mem + (size_t)(rowt0 - 8192) * 512);
        _Float16* dstpk = (rowt0 < 8192) ? f16pk : m16pk;
        const int rowb = blockIdx.x & 511;      // 16-row block index in tensor
#pragma unroll
        for (int i = 0; i < 8; ++i) {
            int li = t + i * 256;               // float4 index in tile [0,2048)
            int r  = li >> 7;                   // 128 float4 per row
            int c4 = (li & 127) * 4;
            float4 v = *(const float4*)&src[(size_t)r * 512 + c4];
            half4 h;
            h[0] = (_Float16)v.x; h[1] = (_Float16)v.y;
            h[2] = (_Float16)v.z; h[3] = (_Float16)v.w;
            *(half4*)&xl[r * 520 + c4] = h;
        }
        __syncthreads();
        half8* dst = (half8*)dstpk;
#pragma unroll
        for (int i = 0; i < 4; ++i) {
            int u = t + i * 256;                // unit index [0,1024)
            int j = u >> 4, ri = u & 15;
            half8 v = *(const half8*)&xl[ri * 520 + j * 8];
            dst[(size_t)rowb * 1024 + u] = v;
        }
    } else if (blockIdx.x < 1536) {
        size_t i4 = (size_t)((blockIdx.x - 1024) * 256 + threadIdx.x) * 4;  // [0, 524288)
        const float* src; _Float16* dst; size_t off;
        if (i4 < 262144ull) { src = wq; dst = wq16; off = i4; }
        else                { src = wk; dst = wk16; off = i4 - 262144ull; }
        int col = (int)(off >> 9);              // W row-major [col][in], 512 wide
        int in0 = (int)(off & 511);             // multiple of 4
        float4 v = *(const float4*)&src[off];
        half4 h;
        h[0] = (_Float16)v.x; h[1] = (_Float16)v.y;
        h[2] = (_Float16)v.z; h[3] = (_Float16)v.w;
        _Float16* base = dst + (size_t)((col >> 4) * 8192 + (in0 >> 3) * 128 +
                                        (col & 15) * 8 + ((in0 >> 2) & 1) * 4);
        *(half4*)base = h;
    } else {
        int cid = (blockIdx.x - 1536) * 256 + threadIdx.x;
        int kb  = cid >> 11;
        int rem = cid & 2047;
        int db  = rem >> 6;
        int gc  = rem & 63;
        int g   = gc >> 4, c = gc & 15;
        const float* src = Mem + (size_t)(kb * 32 + g * 8) * H + db * 16 + c;
        half8 v;
#pragma unroll
        for (int j = 0; j < 8; ++j) v[j] = (_Float16)src[(size_t)j * H];
        vp[cid] = v;
    }
}

// ---------------------------------------------------------------------------
// K1: both projection GEMMs in one launch (blockIdx.z selects q/k problem).
// out = fp16(X @ W^T + b). A/B loads: contiguous 1 KB wave-reads (R17).
// Epilogue: C-tile -> LDS ct[128][68] (pad 68 kills bank conflicts), then
//   z=0: q16 row-major, 8 threads/row -> 128B segments.
//   z=1: kpk B-frag order, 64 consecutive threads -> 1KB contiguous.
// Grid (64, 8, 2), 32 rows/wave.
// ---------------------------------------------------------------------------
__global__ __launch_bounds__(256, 4)
void proj_kernel(const _Float16* __restrict__ Xq, const _Float16* __restrict__ Wq16,
                 const float* __restrict__ bq, _Float16* __restrict__ oq,
                 const _Float16* __restrict__ Xk, const _Float16* __restrict__ Wk16,
                 const float* __restrict__ bk, _Float16* __restrict__ ok) {
    __shared__ _Float16 ct[128 * 68];          // 17.4 KB C-tile, padded

    const _Float16* X16 = blockIdx.z ? Xk : Xq;
    const _Float16* W16 = blockIdx.z ? Wk16 : Wq16;
    const float*    bias = blockIdx.z ? bk : bq;
    _Float16*       out = blockIdx.z ? ok : oq;

    const int t = threadIdx.x;
    const int lane = t & 63;
    const int wave = t >> 6;
    const int rowb0 = blockIdx.x * 8 + wave * 2;   // 16-row block index
    const int col0 = blockIdx.y * 64;
    const int colb0 = col0 >> 4;
    const int lr = lane & 15, lq = lane >> 4;

    floatx4 acc[2][4];
#pragma unroll
    for (int rt = 0; rt < 2; ++rt)
#pragma unroll
        for (int nt = 0; nt < 4; ++nt) { acc[rt][nt][0] = 0.f; acc[rt][nt][1] = 0.f; acc[rt][nt][2] = 0.f; acc[rt][nt][3] = 0.f; }

    const half8* xb = (const half8*)X16;
    const half8* wbase = (const half8*)W16;

#pragma unroll
    for (int kk = 0; kk < 16; ++kk) {
        half8 a0 = xb[(size_t)rowb0 * 1024 + kk * 64 + lq * 16 + lr];
        half8 a1 = xb[(size_t)(rowb0 + 1) * 1024 + kk * 64 + lq * 16 + lr];
#pragma unroll
        for (int nt = 0; nt < 4; ++nt) {
            half8 bf = wbase[(size_t)(colb0 + nt) * 1024 + kk * 64 + lq * 16 + lr];
            acc[0][nt] = MFMA16(a0, bf, acc[0][nt]);
            acc[1][nt] = MFMA16(a1, bf, acc[1][nt]);
        }
    }

    // ---- C-frag + bias -> LDS tile (2-way-max bank aliasing) ----
#pragma unroll
    for (int nt = 0; nt < 4; ++nt) {
        float b = bias[col0 + nt * 16 + lr];
#pragma unroll
        for (int rt = 0; rt < 2; ++rt)
#pragma unroll
            for (int r = 0; r < 4; ++r) {
                int lrow = wave * 32 + rt * 16 + lq * 4 + r;
                ct[lrow * 68 + nt * 16 + lr] = (_Float16)(acc[rt][nt][r] + b);
            }
    }
    __syncthreads();

    if (blockIdx.z == 0) {
        // Q row-major: unit u = row*8 + c8; 8 threads/row -> 128B segments.
        half8* outq = (half8*)out;
#pragma unroll
        for (int i = 0; i < 4; ++i) {
            int u = t + i * 256;
            int row = u >> 3, c8 = u & 7;
            half8 v = *(const half8*)&ct[row * 68 + c8 * 8];
            outq[(size_t)(blockIdx.x * 128 + row) * 64 + (col0 >> 3) + c8] = v;
        }
    } else {
        // K B-frag order: kpk[kt*2048 + c*1024 + kk*64 + g*16 + cc] =
        // K[kt*32 + c*16 + cc][kk*32 + g*8 .. +8]; 64 consecutive threads
        // write 1KB contiguous.
        half8* outk = (half8*)out;
#pragma unroll
        for (int i = 0; i < 4; ++i) {
            int u = t + i * 256;
            int ktl = u >> 8;            // 0..3
            int c   = (u >> 7) & 1;
            int kkl = (u >> 6) & 1;
            int g   = (u >> 4) & 3;
            int cc  = u & 15;
            int lkey = ktl * 32 + c * 16 + cc;     // local row 0..127
            int ld   = kkl * 32 + g * 8;           // local d 0..63
            half8 v = *(const half8*)&ct[lkey * 68 + ld];
            outk[(size_t)(blockIdx.x * 4 + ktl) * 2048 + c * 1024 +
                 ((col0 >> 5) + kkl) * 64 + g * 16 + cc] = v;
        }
    }
}

// ---------------------------------------------------------------------------
// K2: flash attention, 2-barrier pipelined (R11 schedule). K now pre-packed
// in klds B-frag order (kpk), so the K-DMA source is linear: unit tid+i*512.
// blockIdx.x = rbk*4+slice; 128 q-rows per block (8 waves x 16-row stripe),
// slice owns 2048 keys as 64 tiles of 32 keys.
// ---------------------------------------------------------------------------
__global__ __launch_bounds__(512, 2)
void flash_kernel(const _Float16* __restrict__ q16, const _Float16* __restrict__ kpk,
                  const half8* __restrict__ vp, _Float16* __restrict__ opart,
                  float* __restrict__ mpart, float* __restrict__ lpart) {
    __shared__ half8 klds[2][2048];        // 2 x 32 KB: K tiles, B-frag order
    __shared__ half8 vlds[2][2048];        // 2 x 32 KB: V tiles, packed order
    __shared__ _Float16 plds[2][128 * 36]; // 2 x 9 KB: P, stride 36
    __shared__ float alds[2][128];         // per-row rescale factors, dbuf
    __shared__ float llds[128];            // final per-row l
    __shared__ int flagw[2][8];            // per-wave trigger flag, dbuf

    const int tid = threadIdx.x;
    const int lane = tid & 63;
    const int wave = tid >> 6;
    const int rbk = blockIdx.x >> 2;
    const int slice = blockIdx.x & 3;
    const int row0 = rbk * 128;
    const int lr = lane & 15, lq = lane >> 4;

    const half8* kbase = (const half8*)kpk;

    // Q stripe for QK: lane holds q16[row0+wave*16+lr][kk*32+lq*8 ..]
    const half8* qrow = (const half8*)(q16 + (size_t)(row0 + wave * 16 + lr) * H);
    half8 qf[16];
#pragma unroll
    for (int kk = 0; kk < 16; ++kk) qf[kk] = qrow[kk * 4 + lq];

    floatx4 o[8][4];
#pragma unroll
    for (int rb = 0; rb < 8; ++rb)
#pragma unroll
        for (int f = 0; f < 4; ++f) { o[rb][f][0] = 0.f; o[rb][f][1] = 0.f; o[rb][f][2] = 0.f; o[rb][f][3] = 0.f; }
    float m[4], l[4];
#pragma unroll
    for (int r = 0; r < 4; ++r) { m[r] = -1e30f; l[r] = 0.f; }

    // prologue DMA: K(0) -> klds[0], V(0) -> vlds[0], K(1) -> klds[1]
    {
        const int kt0 = slice * 64;
        const half8* ksrc0 = kbase + (size_t)kt0 * 2048;
        const half8* vsrc0 = vp + (size_t)kt0 * 2048;
#pragma unroll
        for (int i = 0; i < 4; ++i) dma16(&klds[0][tid + i * 512], ksrc0 + tid + i * 512);
#pragma unroll
        for (int i = 0; i < 4; ++i) dma16(&vlds[0][tid + i * 512], &vsrc0[tid + i * 512]);
        const half8* ksrc1 = kbase + (size_t)(kt0 + 1) * 2048;
#pragma unroll
        for (int i = 0; i < 4; ++i) dma16(&klds[1][tid + i * 512], ksrc1 + tid + i * 512);
    }

    for (int tt = 0; tt < 64; ++tt) {
        const int b = tt & 1;

        // BAR1: keep 8 newest loads (V(tt), K(tt+1)) in flight; older drained.
        asm volatile("s_waitcnt vmcnt(8) lgkmcnt(0)" ::: "memory");
        __builtin_amdgcn_s_barrier();

        if (tt > 0) {
            const int q1 = b ^ 1;
            // ---- deferred rescale, gated per 16-row chunk (overlapped) ----
#pragma unroll
            for (int rb = 0; rb < 8; ++rb) {
                if (flagw[q1][rb]) {
                    float a0 = alds[q1][rb * 16 + lq * 4 + 0];
                    float a1 = alds[q1][rb * 16 + lq * 4 + 1];
                    float a2 = alds[q1][rb * 16 + lq * 4 + 2];
                    float a3 = alds[q1][rb * 16 + lq * 4 + 3];
#pragma unroll
                    for (int f = 0; f < 4; ++f) {
                        o[rb][f][0] *= a0; o[rb][f][1] *= a1;
                        o[rb][f][2] *= a2; o[rb][f][3] *= a3;
                    }
                }
            }
            // ---- PV(tt-1): overlaps QK ds_reads ----
            __builtin_amdgcn_s_setprio(1);
            half8 vf[4];
#pragma unroll
            for (int f = 0; f < 4; ++f) vf[f] = vlds[q1][(wave * 4 + f) * 64 + lane];
#pragma unroll
            for (int rb = 0; rb < 8; ++rb) {
                half8 pfr = *(const half8*)&plds[q1][(rb * 16 + lr) * 36 + lq * 8];
#pragma unroll
                for (int f = 0; f < 4; ++f) o[rb][f] = MFMA16(pfr, vf[f], o[rb][f]);
            }
            __builtin_amdgcn_s_setprio(0);
        }

        // ---- QK^T(tt): S[16 x 32] per wave, K frags from klds[b] ----
        __builtin_amdgcn_s_setprio(1);
        floatx4 s0 = {0.f, 0.f, 0.f, 0.f}, s1 = {0.f, 0.f, 0.f, 0.f};
#pragma unroll
        for (int kk = 0; kk < 16; ++kk) {
            s0 = MFMA16(qf[kk], klds[b][kk * 64 + lane], s0);
            s1 = MFMA16(qf[kk], klds[b][1024 + kk * 64 + lane], s1);
        }
        __builtin_amdgcn_s_setprio(0);

        // ---- softmax(tt): per-wave trigger (16 rows) ----
        float tm[4]; int trig = 0;
#pragma unroll
        for (int r = 0; r < 4; ++r) {
            tm[r] = fmaxf(s0[r], s1[r]);
            trig |= (tm[r] > m[r] + 10.f) ? 1 : 0;
        }
        const int trigany = __any(trig) ? 1 : 0;
        if (lane == 0) flagw[b][wave] = trigany;
        if (trigany) {
            float al[4];
#pragma unroll
            for (int r = 0; r < 4; ++r) {
                float mx = tm[r];
                mx = fmaxf(mx, __shfl_xor(mx, 1));
                mx = fmaxf(mx, __shfl_xor(mx, 2));
                mx = fmaxf(mx, __shfl_xor(mx, 4));
                mx = fmaxf(mx, __shfl_xor(mx, 8));
                float mn = (mx > m[r] + 10.f) ? mx : m[r];
                al[r] = __expf(m[r] - mn);
                m[r] = mn;
                l[r] *= al[r];
            }
            if (lr == 0) {
#pragma unroll
                for (int r = 0; r < 4; ++r) alds[b][wave * 16 + lq * 4 + r] = al[r];
            }
        }

        // ---- exp, l accumulate, P -> plds[b] (overlapped; dbuf) ----
#pragma unroll
        for (int r = 0; r < 4; ++r) {
            float p0 = __expf(s0[r] - m[r]);
            float p1 = __expf(s1[r] - m[r]);
            l[r] += p0 + p1;
            plds[b][(wave * 16 + lq * 4 + r) * 36 + lr]      = (_Float16)p0;
            plds[b][(wave * 16 + lq * 4 + r) * 36 + 16 + lr] = (_Float16)p1;
        }

        // BAR2: all waves' klds[b]/vlds[b^1] reads consumed; LDS writes landed.
        asm volatile("s_waitcnt lgkmcnt(0)" ::: "memory");
        __builtin_amdgcn_s_barrier();

        // ---- issue DMA: V(tt+1) -> vlds[(tt+1)&1], K(tt+2) -> klds[b] ----
        // Tail-clamped (dead-buffer writes) to keep vmcnt count uniform at 8.
        {
            int vt = tt + 1; if (vt > 63) vt = 63;
            int kt2 = tt + 2; if (kt2 > 63) kt2 = 63;
            const half8* vsrc = vp + (size_t)(slice * 64 + vt) * 2048;
#pragma unroll
            for (int i = 0; i < 4; ++i) dma16(&vlds[(tt + 1) & 1][tid + i * 512], &vsrc[tid + i * 512]);
            const half8* ksrc = kbase + (size_t)(slice * 64 + kt2) * 2048;
#pragma unroll
            for (int i = 0; i < 4; ++i) dma16(&klds[b][tid + i * 512], ksrc + tid + i * 512);
        }
    }

    // ---- epilogue: rescale(63) + PV(63); all P/alds/flagw written pre-BAR2(63)
    asm volatile("s_waitcnt lgkmcnt(0)" ::: "memory");
    {
#pragma unroll
        for (int rb = 0; rb < 8; ++rb) {
            if (flagw[1][rb]) {
                float a0 = alds[1][rb * 16 + lq * 4 + 0];
                float a1 = alds[1][rb * 16 + lq * 4 + 1];
                float a2 = alds[1][rb * 16 + lq * 4 + 2];
                float a3 = alds[1][rb * 16 + lq * 4 + 3];
#pragma unroll
                for (int f = 0; f < 4; ++f) {
                    o[rb][f][0] *= a0; o[rb][f][1] *= a1;
                    o[rb][f][2] *= a2; o[rb][f][3] *= a3;
                }
            }
        }
        __builtin_amdgcn_s_setprio(1);
        half8 vf[4];
#pragma unroll
        for (int f = 0; f < 4; ++f) vf[f] = vlds[1][(wave * 4 + f) * 64 + lane];
#pragma unroll
        for (int rb = 0; rb < 8; ++rb) {
            half8 pfr = *(const half8*)&plds[1][(rb * 16 + lr) * 36 + lq * 8];
#pragma unroll
            for (int f = 0; f < 4; ++f) o[rb][f] = MFMA16(pfr, vf[f], o[rb][f]);
        }
        __builtin_amdgcn_s_setprio(0);
    }

    // ---- final l reduction over the 16 lr lanes ----
#pragma unroll
    for (int r = 0; r < 4; ++r) {
        float lv = l[r];
        lv += __shfl_xor(lv, 1); lv += __shfl_xor(lv, 2);
        lv += __shfl_xor(lv, 4); lv += __shfl_xor(lv, 8);
        l[r] = lv;
    }
    if (lr == 0) {
#pragma unroll
        for (int r = 0; r < 4; ++r) {
            int row = wave * 16 + lq * 4 + r;
            llds[row] = l[r];
            mpart[slice * NROWS + row0 + row] = m[r];
            lpart[slice * NROWS + row0 + row] = l[r];
        }
    }
    __syncthreads();

    // ---- normalized O store (fp16); wave owns d-slice [wave*64, +64) ----
    _Float16* ob = opart + (size_t)slice * NROWS * H;
#pragma unroll
    for (int rb = 0; rb < 8; ++rb) {
#pragma unroll
        for (int rr = 0; rr < 4; ++rr) {
            float linv = 1.0f / llds[rb * 16 + lq * 4 + rr];
            size_t row = row0 + rb * 16 + lq * 4 + rr;
#pragma unroll
            for (int f = 0; f < 4; ++f)
                ob[row * H + wave * 64 + f * 16 + lr] = (_Float16)(o[rb][f][rr] * linv);
        }
    }
}

// ---------------------------------------------------------------------------
// K3: merge normalized slice partials, 4 outputs/thread, vectorized.
// ---------------------------------------------------------------------------
__global__ void merge_kernel(const _Float16* __restrict__ opart, const float* __restrict__ mpart,
                             const float* __restrict__ lpart, const float* __restrict__ F,
                             float* __restrict__ out) {
    int gid = blockIdx.x * 256 + threadIdx.x;
    size_t idx4 = (size_t)gid * 4;
    int row = (int)(idx4 >> 9);
    float m0 = mpart[row], m1 = mpart[NROWS + row], m2 = mpart[2 * NROWS + row], m3 = mpart[3 * NROWS + row];
    float ms = fmaxf(fmaxf(m0, m1), fmaxf(m2, m3));
    float w0 = __expf(m0 - ms) * lpart[row];
    float w1 = __expf(m1 - ms) * lpart[NROWS + row];
    float w2 = __expf(m2 - ms) * lpart[2 * NROWS + row];
    float w3 = __expf(m3 - ms) * lpart[3 * NROWS + row];
    float rdenom = 1.0f / (w0 + w1 + w2 + w3);
    size_t stride = (size_t)NROWS * H;
    half4 o0 = *(const half4*)&opart[idx4];
    half4 o1 = *(const half4*)&opart[stride + idx4];
    half4 o2 = *(const half4*)&opart[2 * stride + idx4];
    half4 o3 = *(const half4*)&opart[3 * stride + idx4];
    float4 Fv = *(const float4*)&F[idx4];
    float4 res;
    res.x = 0.5f * Fv.x + 0.5f * ((w0 * (float)o0[0] + w1 * (float)o1[0] + w2 * (float)o2[0] + w3 * (float)o3[0]) * rdenom);
    res.y = 0.5f * Fv.y + 0.5f * ((w0 * (float)o0[1] + w1 * (float)o1[1] + w2 * (float)o2[1] + w3 * (float)o3[1]) * rdenom);
    res.z = 0.5f * Fv.z + 0.5f * ((w0 * (float)o0[2] + w1 * (float)o1[2] + w2 * (float)o2[2] + w3 * (float)o3[2]) * rdenom);
    res.w = 0.5f * Fv.w + 0.5f * ((w0 * (float)o0[3] + w1 * (float)o1[3] + w2 * (float)o2[3] + w3 * (float)o3[3]) * rdenom);
    *(float4*)&out[idx4] = res;
}

// ---------------------------------------------------------------------------
// Workspace (~58 MB):
//   [ 0M,  8M) q16   [ 8M, 16M) kpk (B-frag packed)   [16M, 24M) vp
//   [24M, 56M) opart fp16 ; f16pk aliases opart[24M,32M), m16pk aliases
//   opart[32M,40M) — both dead before flash writes opart (stream-ordered).
//   [56M,+128K) mpart  [+128K] lpart  [57M,+1M) wq16/wk16 (packed layout)
// ---------------------------------------------------------------------------
extern "C" void kernel_launch(void* const* d_in, const int* in_sizes, int n_in,
                              void* d_out, int out_size, void* d_ws, size_t ws_size,
                              hipStream_t stream) {
    const float* F   = (const float*)d_in[0];
    const float* Mem = (const float*)d_in[1];
    const float* Wq  = (const float*)d_in[2];
    const float* bq  = (const float*)d_in[3];
    const float* Wk  = (const float*)d_in[4];
    const float* bk  = (const float*)d_in[5];
    float* out = (float*)d_out;

    char* ws = (char*)d_ws;
    _Float16* q16   = (_Float16*)(ws);
    _Float16* kpk   = (_Float16*)(ws + (8ull << 20));
    half8*    vp    = (half8*)(ws + (16ull << 20));
    _Float16* opart = (_Float16*)(ws + (24ull << 20));
    _Float16* f16pk = (_Float16*)(ws + (24ull << 20));   // aliases opart slice 0
    _Float16* m16pk = (_Float16*)(ws + (32ull << 20));   // aliases opart slice 1
    float*    mpart = (float*)(ws + (56ull << 20));
    float*    lpart = (float*)(ws + (56ull << 20) + (128ull << 10));
    _Float16* wq16  = (_Float16*)(ws + (57ull << 20));
    _Float16* wk16  = (_Float16*)(ws + (57ull << 20) + (512ull << 10));

    castpack_kernel<<<3584, 256, 0, stream>>>(F, Mem, Wq, Wk, f16pk, m16pk, wq16, wk16, vp);
    proj_kernel<<<dim3(64, 8, 2), 256, 0, stream>>>(f16pk, wq16, bq, q16, m16pk, wk16, bk, kpk);
    flash_kernel<<<256, 512, 0, stream>>>(q16, kpk, vp, opart, mpart, lpart);
    merge_kernel<<<4096, 256, 0, stream>>>(opart, mpart, lpart, F, out);
}